// Round 15
// baseline (248.029 us; speedup 1.0000x reference)
//
#include <hip/hip_runtime.h>
#include <stdint.h>

// DCNv2 fused forward (B=8, C=256, H=W=64, OC=256, 3x3, pad=1, stride=1, DG=1)
// R20 (v17): R19 geometry (grid 1024, 512thr, per-wave 64oc x 16pos, 1 B-read/
// step — PASSED correctness) + R17-proven in-phase 1-deep A-prefetch restored.
// R19 post-mortem: MfmaUtil 11% @ 47% occupancy = MFMA phase latency-serial
// (LOAD_A feeding MFMA_STEP directly, ~300cy L2 stall x 9 steps; compiler
// didn't hoist at VGPR=40). Fix: named aCur/aNxt alternation, LOAD_A(tp+1)
// issued before MFMA_STEP(tp) — same in-phase pattern R17 proved.
// launch_bounds(512,8): VGPR <= 64 (occupancy cliff at 64 per m69) so grid
// 1024 can reach 4 blocks/CU = 32 waves/CU.
// Numerics (R16+): xtfh fp16, bw2 hi-only fp16 x64, single-product fp16 MFMA,
// /64 epilogue. Measured absmax 2^-7 vs 2.86e-2 gate.
// No loop-backedge-carried VMEM regs (R5/R10/R11 cursed pattern avoided).

typedef __attribute__((ext_vector_type(8))) _Float16 half8;
typedef __attribute__((ext_vector_type(2))) __fp16 fp16x2;
typedef __attribute__((ext_vector_type(4))) float floatx4;
typedef __attribute__((ext_vector_type(4))) unsigned int uintx4;

#define MFMA16(A, B, C) __builtin_amdgcn_mfma_f32_16x16x32_f16(A, B, C, 0, 0, 0)

__device__ __forceinline__ unsigned short f16_bits_rne(float v) {
    _Float16 hf = (_Float16)v;               // v_cvt_f16_f32 (RNE)
    union { _Float16 f; unsigned short s; } a; a.f = hf;
    return a.s;
}

// pack 8 f32 -> 8 fp16 (4x cvt_pkrtz)
__device__ __forceinline__ void pack8(const float* vals, uintx4& pkH) {
#pragma unroll
    for (int p = 0; p < 4; p++) {
        fp16x2 h = __builtin_amdgcn_cvt_pkrtz(vals[2 * p], vals[2 * p + 1]);
        union { fp16x2 v; unsigned int u; } ch; ch.v = h;
        pkH[p] = ch.u;
    }
}

__device__ __forceinline__ void mk_coords(int tap, int ho, int wo,
    float offy, float offx, float m,
    int& yx00, int& yx01, int& yx10, int& yx11,
    float& w00, float& w01, float& w10, float& w11) {
    float py = (float)(tap / 3) + (float)(ho - 1) + offy;
    float px = (float)(tap % 3) + (float)(wo - 1) + offx;
    float y0f = floorf(py), x0f = floorf(px);
    float wy1 = py - y0f, wx1 = px - x0f;
    float wy0 = 1.f - wy1, wx0 = 1.f - wx1;
    int y0 = (int)y0f, x0 = (int)x0f, y1 = y0 + 1, x1 = x0 + 1;
    bool vy0 = (y0 >= 0) && (y0 < 64), vy1 = (y1 >= 0) && (y1 < 64);
    bool vx0 = (x0 >= 0) && (x0 < 64), vx1 = (x1 >= 0) && (x1 < 64);
    int cy0 = min(max(y0, 0), 63), cy1 = min(max(y1, 0), 63);
    int cx0 = min(max(x0, 0), 63), cx1 = min(max(x1, 0), 63);
    yx00 = cy0 * 64 + cx0; yx01 = cy0 * 64 + cx1;
    yx10 = cy1 * 64 + cx0; yx11 = cy1 * 64 + cx1;
    w00 = wy0 * wx0 * m * ((vy0 && vx0) ? 1.f : 0.f);
    w01 = wy0 * wx1 * m * ((vy0 && vx1) ? 1.f : 0.f);
    w10 = wy1 * wx0 * m * ((vy1 && vx0) ? 1.f : 0.f);
    w11 = wy1 * wx1 * m * ((vy1 && vx1) ? 1.f : 0.f);
}

// ---- fused prep (R17-proven): blocks 0..2047 transpose x -> xtfh fp16;
//      blocks 2048..4351 weight*64 -> bw2 hi-only fp16 ----
__global__ __launch_bounds__(256) void k_prep(const float* __restrict__ x,
                                              const float* __restrict__ w,
                                              unsigned short* __restrict__ xtfh,
                                              unsigned short* __restrict__ bw2) {
    __shared__ float T[64][65];
    const int blk = blockIdx.x;
    const int t = threadIdx.x;
    if (blk < 2048) {
        const int b = blk >> 8;
        const int ct = (blk >> 6) & 3;
        const int tt = blk & 63;
        const int jj = t & 63, i4 = t >> 6;
        const float* xb = x + ((size_t)b << 20);
#pragma unroll 4
        for (int ii = 0; ii < 16; ii++) {
            int i = ii * 4 + i4;
            T[i][jj] = xb[((size_t)(ct * 64 + i) << 12) + tt * 64 + jj];
        }
        __syncthreads();
        unsigned short* ob = xtfh + ((size_t)b << 20);
#pragma unroll 4
        for (int ii = 0; ii < 16; ii++) {
            int jo = ii * 4 + i4;
            ob[((size_t)(tt * 64 + jo) << 8) + ct * 64 + jj] = f16_bits_rne(T[jj][jo]);
        }
    } else {
        int tid = (blk - 2048) * 256 + t;   // 72*8192 = 589824
        int j = tid & 7;
        int oc = (tid >> 3) & 255;
        int c = (tid >> 11) & 3;
        int step = tid >> 13;
        int ktap = step >> 3;
        int ch = ((step & 7) << 5) + (c << 3) + j;
        float v = w[oc * 2304 + ch * 9 + ktap] * 64.f;
        bw2[tid] = f16_bits_rne(v);
    }
}

// ---- main (grid 1024, 512 thr, chunk-major phases, single-product fp16) ----
__global__ __launch_bounds__(512, 8) void k_dcn_v17(
    const float* __restrict__ offset,  // (8,18,64,64)
    const float* __restrict__ mask,    // (8,9,64,64)
    const float* __restrict__ bias,    // (256,)
    const unsigned short* __restrict__ xtfh, // (8,4096,256) fp16
    const unsigned short* __restrict__ bw2,  // (72,4,256,8) fp16
    float* __restrict__ out)           // (8,256,64,64)
{
    // B region: [slot9(tap)][chunk4(stride 272)][pos32][8]; slot = 1088 ush
    __shared__ __align__(16) unsigned short Bs[9 * 1088];

    const int t = threadIdx.x;         // 0..511
    const int tile = blockIdx.x;       // 0..1023
    const int b = tile & 7;            // XCD/L2 locality
    const int hp = tile >> 3;          // 0..127
    const int ho = hp >> 1;            // 0..63
    const int hh = hp & 1;             // pos half (0/1)

    const int w8 = t >> 6;             // wave 0..7
    const int ocg = w8 >> 1;           // 0..3 (64-oc group)
    const int pg = w8 & 1;             // 0..1 (16-pos group within 32)
    const int quad = (t >> 4) & 3, l15 = t & 15;

    const int g = t >> 7;              // GEN group 0..3 (wave-uniform)
    const int th = t & 127;
    const int gpos = th >> 2;          // 0..31
    const int gseg = th & 3;
    const int wo = (hh << 5) + gpos;
    const int spos = (ho << 6) + wo;
    const unsigned short* xh = xtfh + ((size_t)b << 20);

    // A fragment base: [step][chunk=quad][oc][8]; oc = ocg*64 + i*16 + l15
    const unsigned short* aBase = bw2 + quad * 2048 + (((ocg << 6) + l15) << 3);

    floatx4 acc[4];
#pragma unroll
    for (int i = 0; i < 4; i++) acc[i] = (floatx4){0.f, 0.f, 0.f, 0.f};

    // ---- prologue: this GEN group's taps {g, g+4, 8} offset/mask ----
    float om0s[3], om1s[3], omms[3];
#pragma unroll
    for (int s = 0; s < 3; ++s) {
        const int tap = (s == 2) ? 8 : (g + (s << 2));
        om0s[s] = offset[((size_t)(b * 18 + 2 * tap) << 12) + spos];
        om1s[s] = offset[((size_t)(b * 18 + 2 * tap + 1) << 12) + spos];
        omms[s] = mask[((size_t)(b * 9 + tap) << 12) + spos];
    }

    half8 aCur[4], aNxt[4];
    half8 crn[4];
    int yx[4];
    float ws[4];

#define MK(S) do { const int _tap = ((S) == 2) ? 8 : (g + ((S) << 2));      \
    mk_coords(_tap, ho, wo, om0s[S], om1s[S], omms[S],                      \
        yx[0], yx[1], yx[2], yx[3], ws[0], ws[1], ws[2], ws[3]); } while (0)

#define LOAD_CRN(C) do {                                                    \
    const int cb = ((C) << 5) + (gseg << 3);                                \
    crn[0] = *(const half8*)(xh + ((size_t)yx[0] << 8) + cb);               \
    crn[1] = *(const half8*)(xh + ((size_t)yx[1] << 8) + cb);               \
    crn[2] = *(const half8*)(xh + ((size_t)yx[2] << 8) + cb);               \
    crn[3] = *(const half8*)(xh + ((size_t)yx[3] << 8) + cb);               \
    } while (0)

#define GEN_WRITE(SLOT) do {                                                \
    float vals[8];                                                          \
    _Pragma("unroll")                                                       \
    for (int q = 0; q < 8; q++) {                                           \
        vals[q] = ws[0] * (float)crn[0][q] + ws[1] * (float)crn[1][q]       \
                + ws[2] * (float)crn[2][q] + ws[3] * (float)crn[3][q];      \
    }                                                                       \
    uintx4 pkH;                                                             \
    pack8(vals, pkH);                                                       \
    unsigned short* bp = Bs + (SLOT) * 1088 + gseg * 272 + (gpos << 3);     \
    *(uintx4*)bp = pkH;                                                     \
    } while (0)

#define LOAD_A(DST, STEP) do {                                              \
    const unsigned short* ap = aBase + (size_t)(STEP) * 8192;               \
    DST[0] = *(const half8*)ap;                                             \
    DST[1] = *(const half8*)(ap + 128);                                     \
    DST[2] = *(const half8*)(ap + 256);                                     \
    DST[3] = *(const half8*)(ap + 384);                                     \
    } while (0)

#define MFMA_STEP(SLOT, AREG) do {                                          \
    const unsigned short* Bp = Bs + (SLOT) * 1088 + quad * 272              \
                             + (pg << 7) + (l15 << 3);                      \
    const half8 bH = *(const half8*)Bp;                                     \
    acc[0] = MFMA16(AREG[0], bH, acc[0]);                                   \
    acc[1] = MFMA16(AREG[1], bH, acc[1]);                                   \
    acc[2] = MFMA16(AREG[2], bH, acc[2]);                                   \
    acc[3] = MFMA16(AREG[3], bH, acc[3]);                                   \
    } while (0)

    for (int c = 0; c < 8; ++c) {   // runtime loop (keeps code size in I$)
        // ---- GEN phase: group g does taps {g, g+4, 8(g0)} at chunk c ----
#pragma unroll
        for (int s = 0; s < 3; ++s) {
            if (s < 2 || g == 0) {             // wave-uniform guard
                MK(s);
                LOAD_CRN(c);
                GEN_WRITE((s == 2) ? 8 : (g + (s << 2)));
            }
        }
        __syncthreads();                       // all 9 Bs slots visible

        // ---- MFMA phase: 9 steps (step = tap*8 + c), 1-deep A-prefetch ----
        LOAD_A(aCur, c);
#pragma unroll
        for (int tp = 0; tp < 9; ++tp) {
            if (tp < 8) {
                if ((tp & 1) == 0) LOAD_A(aNxt, (tp + 1) * 8 + c);
                else               LOAD_A(aCur, (tp + 1) * 8 + c);
            }
            if ((tp & 1) == 0) MFMA_STEP(tp, aCur);
            else               MFMA_STEP(tp, aNxt);
        }
        __syncthreads();                       // all reads done before next GEN
    }

    // ---- epilogue: C/D col=l15 -> pos, row=quad*4+r -> oc; undo x64 ----
    float* outb = out + ((size_t)b << 20);
    const int posbase = (ho << 6) + (hh << 5) + (pg << 4);
#pragma unroll
    for (int i = 0; i < 4; i++) {
        const int ocb = (ocg << 6) + (i << 4) + (quad << 2);
#pragma unroll
        for (int r = 0; r < 4; r++) {
            const float bv = bias[ocb + r];
            const int pos = posbase + l15;
            outb[((size_t)(ocb + r) << 12) + pos] = acc[i][r] * 0.015625f + bv;
        }
    }
#undef MK
#undef LOAD_CRN
#undef GEN_WRITE
#undef LOAD_A
#undef MFMA_STEP
}

// ---- fallback (no workspace): R8-proven 3-product path, unchanged ----
__device__ __forceinline__ void split_f16_bits(float v, unsigned int& h, unsigned int& l) {
    _Float16 hf = (_Float16)v;
    float hff = (float)hf;
    _Float16 lf = (_Float16)(v - hff);
    union { _Float16 f; unsigned short s; } a2, b2;
    a2.f = hf; b2.f = lf;
    h = a2.s; l = b2.s;
}
__device__ __forceinline__ void split_pack8(const float* vals, uintx4& pkH, uintx4& pkL) {
#pragma unroll
    for (int p = 0; p < 4; p++) {
        float v0 = vals[2 * p], v1 = vals[2 * p + 1];
        fp16x2 h = __builtin_amdgcn_cvt_pkrtz(v0, v1);
        float h0 = (float)h[0], h1 = (float)h[1];
        fp16x2 l = __builtin_amdgcn_cvt_pkrtz(v0 - h0, v1 - h1);
        union { fp16x2 v; unsigned int u; } ch, cl;
        ch.v = h; cl.v = l;
        pkH[p] = ch.u;
        pkL[p] = cl.u;
    }
}

__global__ __launch_bounds__(256, 2) void k_dcn_fb(
    const float* __restrict__ x, const float* __restrict__ offset,
    const float* __restrict__ mask, const float* __restrict__ weight,
    const float* __restrict__ bias, float* __restrict__ out)
{
    __shared__ __align__(16) unsigned short AsH[256 * 40];
    __shared__ __align__(16) unsigned short AsL[256 * 40];
    __shared__ __align__(16) unsigned short BsH[64 * 40];
    __shared__ __align__(16) unsigned short BsL[64 * 40];
    __shared__ int cY[64][4];
    __shared__ float cW[64][4];

    const int t = threadIdx.x;
    const int tile = blockIdx.x;
    const int b = tile >> 6;
    const int ho = tile & 63;
    const int lane = t & 63, wid = t >> 6, quad = lane >> 4, l15 = lane & 15;
    const int gpos = t >> 2, gseg = t & 3;

    floatx4 acc[4][4];
#pragma unroll
    for (int i = 0; i < 4; i++)
#pragma unroll
        for (int j = 0; j < 4; j++) acc[i][j] = (floatx4){0.f, 0.f, 0.f, 0.f};

    for (int ktap = 0; ktap < 9; ++ktap) {
        __syncthreads();
        if (t < 64) {
            int wo = t;
            int spos = (ho << 6) + wo;
            float offy = offset[(((size_t)(b * 18 + 2 * ktap)) << 12) + spos];
            float offx = offset[(((size_t)(b * 18 + 2 * ktap + 1)) << 12) + spos];
            float m = mask[(((size_t)(b * 9 + ktap)) << 12) + spos];
            int c0, c1, c2, c3; float u0, u1, u2, u3;
            mk_coords(ktap, ho, wo, offy, offx, m, c0, c1, c2, c3, u0, u1, u2, u3);
            cY[t][0] = c0; cY[t][1] = c1; cY[t][2] = c2; cY[t][3] = c3;
            cW[t][0] = u0; cW[t][1] = u1; cW[t][2] = u2; cW[t][3] = u3;
        }
        __syncthreads();
        const int yx00 = cY[gpos][0], yx01 = cY[gpos][1];
        const int yx10 = cY[gpos][2], yx11 = cY[gpos][3];
        const float w00 = cW[gpos][0], w01 = cW[gpos][1];
        const float w10 = cW[gpos][2], w11 = cW[gpos][3];

        for (int cs = 0; cs < 8; ++cs) {
            const int c0 = cs << 5;
            {
                const float* wp = weight + (size_t)t * 2304 + (size_t)c0 * 9 + ktap;
#pragma unroll
                for (int kj = 0; kj < 32; kj += 2) {
                    unsigned int h0, l0u, h1, l1u;
                    split_f16_bits(wp[kj * 9] * 64.f, h0, l0u);
                    split_f16_bits(wp[kj * 9 + 9] * 64.f, h1, l1u);
                    *(unsigned int*)&AsH[t * 40 + kj] = h0 | (h1 << 16);
                    *(unsigned int*)&AsL[t * 40 + kj] = l0u | (l1u << 16);
                }
            }
            {
                const int cb = c0 + (gseg << 3);
                const float* xg = x + ((size_t)b << 20);
                float vals[8];
#pragma unroll
                for (int j = 0; j < 8; j++) {
                    const float* xc = xg + ((size_t)(cb + j) << 12);
                    vals[j] = w00 * xc[yx00] + w01 * xc[yx01] +
                              w10 * xc[yx10] + w11 * xc[yx11];
                }
                uintx4 pkH, pkL;
                split_pack8(vals, pkH, pkL);
                *(uintx4*)&BsH[gpos * 40 + (gseg << 3)] = pkH;
                *(uintx4*)&BsL[gpos * 40 + (gseg << 3)] = pkL;
            }
            __syncthreads();
            half8 aH[4], aL[4], bH[4], bL[4];
#pragma unroll
            for (int i = 0; i < 4; i++) {
                const int rowA = (wid << 6) + (i << 4) + l15;
                aH[i] = *(const half8*)&AsH[rowA * 40 + (quad << 3)];
                aL[i] = *(const half8*)&AsL[rowA * 40 + (quad << 3)];
            }
#pragma unroll
            for (int j = 0; j < 4; j++) {
                const int rowB = (j << 4) + l15;
                bH[j] = *(const half8*)&BsH[rowB * 40 + (quad << 3)];
                bL[j] = *(const half8*)&BsL[rowB * 40 + (quad << 3)];
            }
#pragma unroll
            for (int i = 0; i < 4; i++)
#pragma unroll
                for (int j = 0; j < 4; j++) {
                    acc[i][j] = MFMA16(aH[i], bH[j], acc[i][j]);
                    acc[i][j] = MFMA16(aL[i], bH[j], acc[i][j]);
                    acc[i][j] = MFMA16(aH[i], bL[j], acc[i][j]);
                }
            __syncthreads();
        }
    }
    float* outb = out + ((size_t)b << 20);
    const int posbase = ho << 6;
#pragma unroll
    for (int i = 0; i < 4; i++) {
        const int ocb = (wid << 6) + (i << 4) + (quad << 2);
#pragma unroll
        for (int r = 0; r < 4; r++) {
            const float bv = bias[ocb + r];
#pragma unroll
            for (int j = 0; j < 4; j++) {
                const int pos = posbase + (j << 4) + l15;
                outb[((size_t)(ocb + r) << 12) + pos] = acc[i][j][r] * 0.015625f + bv;
            }
        }
    }
}

extern "C" void kernel_launch(void* const* d_in, const int* in_sizes, int n_in,
                              void* d_out, int out_size, void* d_ws, size_t ws_size,
                              hipStream_t stream) {
    const float* x      = (const float*)d_in[0];
    const float* offset = (const float*)d_in[1];
    const float* mask   = (const float*)d_in[2];
    const float* weight = (const float*)d_in[3];
    const float* bias   = (const float*)d_in[4];
    float* out = (float*)d_out;

    const size_t xtf_bytes = (size_t)8 * 4096 * 256 * 2;       // 16 MB fp16
    const size_t bw2_elems = (size_t)72 * 8192;                // 589824 ush
    const size_t need = xtf_bytes + bw2_elems * 2;             // ~17.1 MB

    if (ws_size >= need) {
        unsigned short* xtfh = (unsigned short*)d_ws;
        unsigned short* bw2 = (unsigned short*)((char*)d_ws + xtf_bytes);
        k_prep<<<2048 + 2304, 256, 0, stream>>>(x, weight, xtfh, bw2);
        k_dcn_v17<<<1024, 512, 0, stream>>>(offset, mask, bias, xtfh, bw2, out);
    } else {
        k_dcn_fb<<<512, 256, 0, stream>>>(x, offset, mask, weight, bias, out);
    }
}

// Round 16
// 238.326 us; speedup vs baseline: 1.0407x; 1.0407x over previous
//
#include <hip/hip_runtime.h>
#include <stdint.h>

// DCNv2 fused forward (B=8, C=256, H=W=64, OC=256, 3x3, pad=1, stride=1, DG=1)
// R21 (v18): R20 with launch_bounds corrected 8 -> 6.
// R20 post-mortem: bounds(512,8) = 64-VGPR budget; kernel needs ~80 ->
// compiler spilled to scratch (VGPR=32, FETCH 22->172 MB, WRITE 41->100 MB,
// MfmaUtil 9%). bounds(512,6) gives ~85 VGPR budget: full in-phase prefetch
// fits, 3 blocks/CU = 24 waves/CU (2x R17's occupancy).
// Geometry (R19/R20-proven correct): grid 1024 (b, ho, pos-half); 512 thr =
// 8 waves = 4 ocgrp x 2 posgrp; per wave 64oc x 16pos, acc[4], ONE B
// ds_read_b128/step; Bs = 9 x 1088 ush (19.6 KB).
// Schedule (R17-proven): chunk-major phases c=0..7, GEN (4 groups x taps
// {g,g+4,8}) -> barrier -> 9 MFMA steps with 1-deep in-phase A-prefetch
// (named aCur/aNxt, no backedge-carried VMEM regs) -> barrier.
// Numerics (R16+-proven): xtfh fp16, bw2 hi-only fp16 x64, single-product
// fp16 MFMA, /64 epilogue. Measured absmax 2^-7 vs 2.86e-2 gate.

typedef __attribute__((ext_vector_type(8))) _Float16 half8;
typedef __attribute__((ext_vector_type(2))) __fp16 fp16x2;
typedef __attribute__((ext_vector_type(4))) float floatx4;
typedef __attribute__((ext_vector_type(4))) unsigned int uintx4;

#define MFMA16(A, B, C) __builtin_amdgcn_mfma_f32_16x16x32_f16(A, B, C, 0, 0, 0)

__device__ __forceinline__ unsigned short f16_bits_rne(float v) {
    _Float16 hf = (_Float16)v;               // v_cvt_f16_f32 (RNE)
    union { _Float16 f; unsigned short s; } a; a.f = hf;
    return a.s;
}

// pack 8 f32 -> 8 fp16 (4x cvt_pkrtz)
__device__ __forceinline__ void pack8(const float* vals, uintx4& pkH) {
#pragma unroll
    for (int p = 0; p < 4; p++) {
        fp16x2 h = __builtin_amdgcn_cvt_pkrtz(vals[2 * p], vals[2 * p + 1]);
        union { fp16x2 v; unsigned int u; } ch; ch.v = h;
        pkH[p] = ch.u;
    }
}

__device__ __forceinline__ void mk_coords(int tap, int ho, int wo,
    float offy, float offx, float m,
    int& yx00, int& yx01, int& yx10, int& yx11,
    float& w00, float& w01, float& w10, float& w11) {
    float py = (float)(tap / 3) + (float)(ho - 1) + offy;
    float px = (float)(tap % 3) + (float)(wo - 1) + offx;
    float y0f = floorf(py), x0f = floorf(px);
    float wy1 = py - y0f, wx1 = px - x0f;
    float wy0 = 1.f - wy1, wx0 = 1.f - wx1;
    int y0 = (int)y0f, x0 = (int)x0f, y1 = y0 + 1, x1 = x0 + 1;
    bool vy0 = (y0 >= 0) && (y0 < 64), vy1 = (y1 >= 0) && (y1 < 64);
    bool vx0 = (x0 >= 0) && (x0 < 64), vx1 = (x1 >= 0) && (x1 < 64);
    int cy0 = min(max(y0, 0), 63), cy1 = min(max(y1, 0), 63);
    int cx0 = min(max(x0, 0), 63), cx1 = min(max(x1, 0), 63);
    yx00 = cy0 * 64 + cx0; yx01 = cy0 * 64 + cx1;
    yx10 = cy1 * 64 + cx0; yx11 = cy1 * 64 + cx1;
    w00 = wy0 * wx0 * m * ((vy0 && vx0) ? 1.f : 0.f);
    w01 = wy0 * wx1 * m * ((vy0 && vx1) ? 1.f : 0.f);
    w10 = wy1 * wx0 * m * ((vy1 && vx0) ? 1.f : 0.f);
    w11 = wy1 * wx1 * m * ((vy1 && vx1) ? 1.f : 0.f);
}

// ---- fused prep (R17-proven): blocks 0..2047 transpose x -> xtfh fp16;
//      blocks 2048..4351 weight*64 -> bw2 hi-only fp16 ----
__global__ __launch_bounds__(256) void k_prep(const float* __restrict__ x,
                                              const float* __restrict__ w,
                                              unsigned short* __restrict__ xtfh,
                                              unsigned short* __restrict__ bw2) {
    __shared__ float T[64][65];
    const int blk = blockIdx.x;
    const int t = threadIdx.x;
    if (blk < 2048) {
        const int b = blk >> 8;
        const int ct = (blk >> 6) & 3;
        const int tt = blk & 63;
        const int jj = t & 63, i4 = t >> 6;
        const float* xb = x + ((size_t)b << 20);
#pragma unroll 4
        for (int ii = 0; ii < 16; ii++) {
            int i = ii * 4 + i4;
            T[i][jj] = xb[((size_t)(ct * 64 + i) << 12) + tt * 64 + jj];
        }
        __syncthreads();
        unsigned short* ob = xtfh + ((size_t)b << 20);
#pragma unroll 4
        for (int ii = 0; ii < 16; ii++) {
            int jo = ii * 4 + i4;
            ob[((size_t)(tt * 64 + jo) << 8) + ct * 64 + jj] = f16_bits_rne(T[jj][jo]);
        }
    } else {
        int tid = (blk - 2048) * 256 + t;   // 72*8192 = 589824
        int j = tid & 7;
        int oc = (tid >> 3) & 255;
        int c = (tid >> 11) & 3;
        int step = tid >> 13;
        int ktap = step >> 3;
        int ch = ((step & 7) << 5) + (c << 3) + j;
        float v = w[oc * 2304 + ch * 9 + ktap] * 64.f;
        bw2[tid] = f16_bits_rne(v);
    }
}

// ---- main (grid 1024, 512 thr, chunk-major phases, single-product fp16) ----
__global__ __launch_bounds__(512, 6) void k_dcn_v18(
    const float* __restrict__ offset,  // (8,18,64,64)
    const float* __restrict__ mask,    // (8,9,64,64)
    const float* __restrict__ bias,    // (256,)
    const unsigned short* __restrict__ xtfh, // (8,4096,256) fp16
    const unsigned short* __restrict__ bw2,  // (72,4,256,8) fp16
    float* __restrict__ out)           // (8,256,64,64)
{
    // B region: [slot9(tap)][chunk4(stride 272)][pos32][8]; slot = 1088 ush
    __shared__ __align__(16) unsigned short Bs[9 * 1088];

    const int t = threadIdx.x;         // 0..511
    const int tile = blockIdx.x;       // 0..1023
    const int b = tile & 7;            // XCD/L2 locality
    const int hp = tile >> 3;          // 0..127
    const int ho = hp >> 1;            // 0..63
    const int hh = hp & 1;             // pos half (0/1)

    const int w8 = t >> 6;             // wave 0..7
    const int ocg = w8 >> 1;           // 0..3 (64-oc group)
    const int pg = w8 & 1;             // 0..1 (16-pos group within 32)
    const int quad = (t >> 4) & 3, l15 = t & 15;

    const int g = t >> 7;              // GEN group 0..3 (wave-uniform)
    const int th = t & 127;
    const int gpos = th >> 2;          // 0..31
    const int gseg = th & 3;
    const int wo = (hh << 5) + gpos;
    const int spos = (ho << 6) + wo;
    const unsigned short* xh = xtfh + ((size_t)b << 20);

    // A fragment base: [step][chunk=quad][oc][8]; oc = ocg*64 + i*16 + l15
    const unsigned short* aBase = bw2 + quad * 2048 + (((ocg << 6) + l15) << 3);

    floatx4 acc[4];
#pragma unroll
    for (int i = 0; i < 4; i++) acc[i] = (floatx4){0.f, 0.f, 0.f, 0.f};

    // ---- prologue: this GEN group's taps {g, g+4, 8} offset/mask ----
    float om0s[3], om1s[3], omms[3];
#pragma unroll
    for (int s = 0; s < 3; ++s) {
        const int tap = (s == 2) ? 8 : (g + (s << 2));
        om0s[s] = offset[((size_t)(b * 18 + 2 * tap) << 12) + spos];
        om1s[s] = offset[((size_t)(b * 18 + 2 * tap + 1) << 12) + spos];
        omms[s] = mask[((size_t)(b * 9 + tap) << 12) + spos];
    }

    half8 aCur[4], aNxt[4];
    half8 crn[4];
    int yx[4];
    float ws[4];

#define MK(S) do { const int _tap = ((S) == 2) ? 8 : (g + ((S) << 2));      \
    mk_coords(_tap, ho, wo, om0s[S], om1s[S], omms[S],                      \
        yx[0], yx[1], yx[2], yx[3], ws[0], ws[1], ws[2], ws[3]); } while (0)

#define LOAD_CRN(C) do {                                                    \
    const int cb = ((C) << 5) + (gseg << 3);                                \
    crn[0] = *(const half8*)(xh + ((size_t)yx[0] << 8) + cb);               \
    crn[1] = *(const half8*)(xh + ((size_t)yx[1] << 8) + cb);               \
    crn[2] = *(const half8*)(xh + ((size_t)yx[2] << 8) + cb);               \
    crn[3] = *(const half8*)(xh + ((size_t)yx[3] << 8) + cb);               \
    } while (0)

#define GEN_WRITE(SLOT) do {                                                \
    float vals[8];                                                          \
    _Pragma("unroll")                                                       \
    for (int q = 0; q < 8; q++) {                                           \
        vals[q] = ws[0] * (float)crn[0][q] + ws[1] * (float)crn[1][q]       \
                + ws[2] * (float)crn[2][q] + ws[3] * (float)crn[3][q];      \
    }                                                                       \
    uintx4 pkH;                                                             \
    pack8(vals, pkH);                                                       \
    unsigned short* bp = Bs + (SLOT) * 1088 + gseg * 272 + (gpos << 3);     \
    *(uintx4*)bp = pkH;                                                     \
    } while (0)

#define LOAD_A(DST, STEP) do {                                              \
    const unsigned short* ap = aBase + (size_t)(STEP) * 8192;               \
    DST[0] = *(const half8*)ap;                                             \
    DST[1] = *(const half8*)(ap + 128);                                     \
    DST[2] = *(const half8*)(ap + 256);                                     \
    DST[3] = *(const half8*)(ap + 384);                                     \
    } while (0)

#define MFMA_STEP(SLOT, AREG) do {                                          \
    const unsigned short* Bp = Bs + (SLOT) * 1088 + quad * 272              \
                             + (pg << 7) + (l15 << 3);                      \
    const half8 bH = *(const half8*)Bp;                                     \
    acc[0] = MFMA16(AREG[0], bH, acc[0]);                                   \
    acc[1] = MFMA16(AREG[1], bH, acc[1]);                                   \
    acc[2] = MFMA16(AREG[2], bH, acc[2]);                                   \
    acc[3] = MFMA16(AREG[3], bH, acc[3]);                                   \
    } while (0)

    for (int c = 0; c < 8; ++c) {   // runtime loop (keeps code size in I$)
        // ---- GEN phase: group g does taps {g, g+4, 8(g0)} at chunk c ----
#pragma unroll
        for (int s = 0; s < 3; ++s) {
            if (s < 2 || g == 0) {             // wave-uniform guard
                MK(s);
                LOAD_CRN(c);
                GEN_WRITE((s == 2) ? 8 : (g + (s << 2)));
            }
        }
        __syncthreads();                       // all 9 Bs slots visible

        // ---- MFMA phase: 9 steps (step = tap*8 + c), 1-deep A-prefetch ----
        LOAD_A(aCur, c);
#pragma unroll
        for (int tp = 0; tp < 9; ++tp) {
            if (tp < 8) {
                if ((tp & 1) == 0) LOAD_A(aNxt, (tp + 1) * 8 + c);
                else               LOAD_A(aCur, (tp + 1) * 8 + c);
            }
            if ((tp & 1) == 0) MFMA_STEP(tp, aCur);
            else               MFMA_STEP(tp, aNxt);
        }
        __syncthreads();                       // all reads done before next GEN
    }

    // ---- epilogue: C/D col=l15 -> pos, row=quad*4+r -> oc; undo x64 ----
    float* outb = out + ((size_t)b << 20);
    const int posbase = (ho << 6) + (hh << 5) + (pg << 4);
#pragma unroll
    for (int i = 0; i < 4; i++) {
        const int ocb = (ocg << 6) + (i << 4) + (quad << 2);
#pragma unroll
        for (int r = 0; r < 4; r++) {
            const float bv = bias[ocb + r];
            const int pos = posbase + l15;
            outb[((size_t)(ocb + r) << 12) + pos] = acc[i][r] * 0.015625f + bv;
        }
    }
#undef MK
#undef LOAD_CRN
#undef GEN_WRITE
#undef LOAD_A
#undef MFMA_STEP
}

// ---- fallback (no workspace): R8-proven 3-product path, unchanged ----
__device__ __forceinline__ void split_f16_bits(float v, unsigned int& h, unsigned int& l) {
    _Float16 hf = (_Float16)v;
    float hff = (float)hf;
    _Float16 lf = (_Float16)(v - hff);
    union { _Float16 f; unsigned short s; } a2, b2;
    a2.f = hf; b2.f = lf;
    h = a2.s; l = b2.s;
}
__device__ __forceinline__ void split_pack8(const float* vals, uintx4& pkH, uintx4& pkL) {
#pragma unroll
    for (int p = 0; p < 4; p++) {
        float v0 = vals[2 * p], v1 = vals[2 * p + 1];
        fp16x2 h = __builtin_amdgcn_cvt_pkrtz(v0, v1);
        float h0 = (float)h[0], h1 = (float)h[1];
        fp16x2 l = __builtin_amdgcn_cvt_pkrtz(v0 - h0, v1 - h1);
        union { fp16x2 v; unsigned int u; } ch, cl;
        ch.v = h; cl.v = l;
        pkH[p] = ch.u;
        pkL[p] = cl.u;
    }
}

__global__ __launch_bounds__(256, 2) void k_dcn_fb(
    const float* __restrict__ x, const float* __restrict__ offset,
    const float* __restrict__ mask, const float* __restrict__ weight,
    const float* __restrict__ bias, float* __restrict__ out)
{
    __shared__ __align__(16) unsigned short AsH[256 * 40];
    __shared__ __align__(16) unsigned short AsL[256 * 40];
    __shared__ __align__(16) unsigned short BsH[64 * 40];
    __shared__ __align__(16) unsigned short BsL[64 * 40];
    __shared__ int cY[64][4];
    __shared__ float cW[64][4];

    const int t = threadIdx.x;
    const int tile = blockIdx.x;
    const int b = tile >> 6;
    const int ho = tile & 63;
    const int lane = t & 63, wid = t >> 6, quad = lane >> 4, l15 = lane & 15;
    const int gpos = t >> 2, gseg = t & 3;

    floatx4 acc[4][4];
#pragma unroll
    for (int i = 0; i < 4; i++)
#pragma unroll
        for (int j = 0; j < 4; j++) acc[i][j] = (floatx4){0.f, 0.f, 0.f, 0.f};

    for (int ktap = 0; ktap < 9; ++ktap) {
        __syncthreads();
        if (t < 64) {
            int wo = t;
            int spos = (ho << 6) + wo;
            float offy = offset[(((size_t)(b * 18 + 2 * ktap)) << 12) + spos];
            float offx = offset[(((size_t)(b * 18 + 2 * ktap + 1)) << 12) + spos];
            float m = mask[(((size_t)(b * 9 + ktap)) << 12) + spos];
            int c0, c1, c2, c3; float u0, u1, u2, u3;
            mk_coords(ktap, ho, wo, offy, offx, m, c0, c1, c2, c3, u0, u1, u2, u3);
            cY[t][0] = c0; cY[t][1] = c1; cY[t][2] = c2; cY[t][3] = c3;
            cW[t][0] = u0; cW[t][1] = u1; cW[t][2] = u2; cW[t][3] = u3;
        }
        __syncthreads();
        const int yx00 = cY[gpos][0], yx01 = cY[gpos][1];
        const int yx10 = cY[gpos][2], yx11 = cY[gpos][3];
        const float w00 = cW[gpos][0], w01 = cW[gpos][1];
        const float w10 = cW[gpos][2], w11 = cW[gpos][3];

        for (int cs = 0; cs < 8; ++cs) {
            const int c0 = cs << 5;
            {
                const float* wp = weight + (size_t)t * 2304 + (size_t)c0 * 9 + ktap;
#pragma unroll
                for (int kj = 0; kj < 32; kj += 2) {
                    unsigned int h0, l0u, h1, l1u;
                    split_f16_bits(wp[kj * 9] * 64.f, h0, l0u);
                    split_f16_bits(wp[kj * 9 + 9] * 64.f, h1, l1u);
                    *(unsigned int*)&AsH[t * 40 + kj] = h0 | (h1 << 16);
                    *(unsigned int*)&AsL[t * 40 + kj] = l0u | (l1u << 16);
                }
            }
            {
                const int cb = c0 + (gseg << 3);
                const float* xg = x + ((size_t)b << 20);
                float vals[8];
#pragma unroll
                for (int j = 0; j < 8; j++) {
                    const float* xc = xg + ((size_t)(cb + j) << 12);
                    vals[j] = w00 * xc[yx00] + w01 * xc[yx01] +
                              w10 * xc[yx10] + w11 * xc[yx11];
                }
                uintx4 pkH, pkL;
                split_pack8(vals, pkH, pkL);
                *(uintx4*)&BsH[gpos * 40 + (gseg << 3)] = pkH;
                *(uintx4*)&BsL[gpos * 40 + (gseg << 3)] = pkL;
            }
            __syncthreads();
            half8 aH[4], aL[4], bH[4], bL[4];
#pragma unroll
            for (int i = 0; i < 4; i++) {
                const int rowA = (wid << 6) + (i << 4) + l15;
                aH[i] = *(const half8*)&AsH[rowA * 40 + (quad << 3)];
                aL[i] = *(const half8*)&AsL[rowA * 40 + (quad << 3)];
            }
#pragma unroll
            for (int j = 0; j < 4; j++) {
                const int rowB = (j << 4) + l15;
                bH[j] = *(const half8*)&BsH[rowB * 40 + (quad << 3)];
                bL[j] = *(const half8*)&BsL[rowB * 40 + (quad << 3)];
            }
#pragma unroll
            for (int i = 0; i < 4; i++)
#pragma unroll
                for (int j = 0; j < 4; j++) {
                    acc[i][j] = MFMA16(aH[i], bH[j], acc[i][j]);
                    acc[i][j] = MFMA16(aL[i], bH[j], acc[i][j]);
                    acc[i][j] = MFMA16(aH[i], bL[j], acc[i][j]);
                }
            __syncthreads();
        }
    }
    float* outb = out + ((size_t)b << 20);
    const int posbase = ho << 6;
#pragma unroll
    for (int i = 0; i < 4; i++) {
        const int ocb = (wid << 6) + (i << 4) + (quad << 2);
#pragma unroll
        for (int r = 0; r < 4; r++) {
            const float bv = bias[ocb + r];
#pragma unroll
            for (int j = 0; j < 4; j++) {
                const int pos = posbase + (j << 4) + l15;
                outb[((size_t)(ocb + r) << 12) + pos] = acc[i][j][r] * 0.015625f + bv;
            }
        }
    }
}

extern "C" void kernel_launch(void* const* d_in, const int* in_sizes, int n_in,
                              void* d_out, int out_size, void* d_ws, size_t ws_size,
                              hipStream_t stream) {
    const float* x      = (const float*)d_in[0];
    const float* offset = (const float*)d_in[1];
    const float* mask   = (const float*)d_in[2];
    const float* weight = (const float*)d_in[3];
    const float* bias   = (const float*)d_in[4];
    float* out = (float*)d_out;

    const size_t xtf_bytes = (size_t)8 * 4096 * 256 * 2;       // 16 MB fp16
    const size_t bw2_elems = (size_t)72 * 8192;                // 589824 ush
    const size_t need = xtf_bytes + bw2_elems * 2;             // ~17.1 MB

    if (ws_size >= need) {
        unsigned short* xtfh = (unsigned short*)d_ws;
        unsigned short* bw2 = (unsigned short*)((char*)d_ws + xtf_bytes);
        k_prep<<<2048 + 2304, 256, 0, stream>>>(x, weight, xtfh, bw2);
        k_dcn_v18<<<1024, 512, 0, stream>>>(offset, mask, bias, xtfh, bw2, out);
    } else {
        k_dcn_fb<<<512, 256, 0, stream>>>(x, offset, mask, weight, bias, out);
    }
}

// Round 17
// 182.858 us; speedup vs baseline: 1.3564x; 1.3033x over previous
//
#include <hip/hip_runtime.h>
#include <stdint.h>

// DCNv2 fused forward (B=8, C=256, H=W=64, OC=256, 3x3, pad=1, stride=1, DG=1)
// R22 (v19): R21 with launch_bounds arg2 corrected 6 -> 3.
// KEY FINDING (R17/R19/R20/R21 VGPR fits): this hipcc treats arg2 as min
// BLOCKS/CU (CUDA semantics), NOT waves/EU: VGPR = 512/(arg2*8/4).
//   (512,4)->64, (512,6)->40, (512,8)->32 — all measured. So "6" forced a
//   42-VGPR budget and spilled the ~77-VGPR prefetch schedule to scratch
//   (FETCH 116MB, WRITE 92MB, MfmaUtil 9.6%). arg2=3: 3 blocks/CU =
//   24 waves/CU (75% occ), VGPR budget ~85 — prefetch fits, no spill.
// Geometry (R19-21-proven correct): grid 1024 (b, ho, pos-half); 512 thr =
// 8 waves = 4 ocgrp x 2 posgrp; per wave 64oc x 16pos, acc[4], ONE B
// ds_read_b128/step; Bs = 9 x 1088 ush (19.6 KB).
// Schedule (R17-proven): chunk-major phases c=0..7, GEN (4 groups x taps
// {g,g+4,8}) -> barrier -> 9 MFMA steps with 1-deep in-phase A-prefetch
// (named aCur/aNxt, no backedge-carried VMEM regs) -> barrier.
// Numerics (R16+-proven): xtfh fp16, bw2 hi-only fp16 x64, single-product
// fp16 MFMA, /64 epilogue. Measured absmax 2^-7 vs 2.86e-2 gate.

typedef __attribute__((ext_vector_type(8))) _Float16 half8;
typedef __attribute__((ext_vector_type(2))) __fp16 fp16x2;
typedef __attribute__((ext_vector_type(4))) float floatx4;
typedef __attribute__((ext_vector_type(4))) unsigned int uintx4;

#define MFMA16(A, B, C) __builtin_amdgcn_mfma_f32_16x16x32_f16(A, B, C, 0, 0, 0)

__device__ __forceinline__ unsigned short f16_bits_rne(float v) {
    _Float16 hf = (_Float16)v;               // v_cvt_f16_f32 (RNE)
    union { _Float16 f; unsigned short s; } a; a.f = hf;
    return a.s;
}

// pack 8 f32 -> 8 fp16 (4x cvt_pkrtz)
__device__ __forceinline__ void pack8(const float* vals, uintx4& pkH) {
#pragma unroll
    for (int p = 0; p < 4; p++) {
        fp16x2 h = __builtin_amdgcn_cvt_pkrtz(vals[2 * p], vals[2 * p + 1]);
        union { fp16x2 v; unsigned int u; } ch; ch.v = h;
        pkH[p] = ch.u;
    }
}

__device__ __forceinline__ void mk_coords(int tap, int ho, int wo,
    float offy, float offx, float m,
    int& yx00, int& yx01, int& yx10, int& yx11,
    float& w00, float& w01, float& w10, float& w11) {
    float py = (float)(tap / 3) + (float)(ho - 1) + offy;
    float px = (float)(tap % 3) + (float)(wo - 1) + offx;
    float y0f = floorf(py), x0f = floorf(px);
    float wy1 = py - y0f, wx1 = px - x0f;
    float wy0 = 1.f - wy1, wx0 = 1.f - wx1;
    int y0 = (int)y0f, x0 = (int)x0f, y1 = y0 + 1, x1 = x0 + 1;
    bool vy0 = (y0 >= 0) && (y0 < 64), vy1 = (y1 >= 0) && (y1 < 64);
    bool vx0 = (x0 >= 0) && (x0 < 64), vx1 = (x1 >= 0) && (x1 < 64);
    int cy0 = min(max(y0, 0), 63), cy1 = min(max(y1, 0), 63);
    int cx0 = min(max(x0, 0), 63), cx1 = min(max(x1, 0), 63);
    yx00 = cy0 * 64 + cx0; yx01 = cy0 * 64 + cx1;
    yx10 = cy1 * 64 + cx0; yx11 = cy1 * 64 + cx1;
    w00 = wy0 * wx0 * m * ((vy0 && vx0) ? 1.f : 0.f);
    w01 = wy0 * wx1 * m * ((vy0 && vx1) ? 1.f : 0.f);
    w10 = wy1 * wx0 * m * ((vy1 && vx0) ? 1.f : 0.f);
    w11 = wy1 * wx1 * m * ((vy1 && vx1) ? 1.f : 0.f);
}

// ---- fused prep (R17-proven): blocks 0..2047 transpose x -> xtfh fp16;
//      blocks 2048..4351 weight*64 -> bw2 hi-only fp16 ----
__global__ __launch_bounds__(256) void k_prep(const float* __restrict__ x,
                                              const float* __restrict__ w,
                                              unsigned short* __restrict__ xtfh,
                                              unsigned short* __restrict__ bw2) {
    __shared__ float T[64][65];
    const int blk = blockIdx.x;
    const int t = threadIdx.x;
    if (blk < 2048) {
        const int b = blk >> 8;
        const int ct = (blk >> 6) & 3;
        const int tt = blk & 63;
        const int jj = t & 63, i4 = t >> 6;
        const float* xb = x + ((size_t)b << 20);
#pragma unroll 4
        for (int ii = 0; ii < 16; ii++) {
            int i = ii * 4 + i4;
            T[i][jj] = xb[((size_t)(ct * 64 + i) << 12) + tt * 64 + jj];
        }
        __syncthreads();
        unsigned short* ob = xtfh + ((size_t)b << 20);
#pragma unroll 4
        for (int ii = 0; ii < 16; ii++) {
            int jo = ii * 4 + i4;
            ob[((size_t)(tt * 64 + jo) << 8) + ct * 64 + jj] = f16_bits_rne(T[jj][jo]);
        }
    } else {
        int tid = (blk - 2048) * 256 + t;   // 72*8192 = 589824
        int j = tid & 7;
        int oc = (tid >> 3) & 255;
        int c = (tid >> 11) & 3;
        int step = tid >> 13;
        int ktap = step >> 3;
        int ch = ((step & 7) << 5) + (c << 3) + j;
        float v = w[oc * 2304 + ch * 9 + ktap] * 64.f;
        bw2[tid] = f16_bits_rne(v);
    }
}

// ---- main (grid 1024, 512 thr, chunk-major phases, single-product fp16) ----
__global__ __launch_bounds__(512, 3) void k_dcn_v19(
    const float* __restrict__ offset,  // (8,18,64,64)
    const float* __restrict__ mask,    // (8,9,64,64)
    const float* __restrict__ bias,    // (256,)
    const unsigned short* __restrict__ xtfh, // (8,4096,256) fp16
    const unsigned short* __restrict__ bw2,  // (72,4,256,8) fp16
    float* __restrict__ out)           // (8,256,64,64)
{
    // B region: [slot9(tap)][chunk4(stride 272)][pos32][8]; slot = 1088 ush
    __shared__ __align__(16) unsigned short Bs[9 * 1088];

    const int t = threadIdx.x;         // 0..511
    const int tile = blockIdx.x;       // 0..1023
    const int b = tile & 7;            // XCD/L2 locality
    const int hp = tile >> 3;          // 0..127
    const int ho = hp >> 1;            // 0..63
    const int hh = hp & 1;             // pos half (0/1)

    const int w8 = t >> 6;             // wave 0..7
    const int ocg = w8 >> 1;           // 0..3 (64-oc group)
    const int pg = w8 & 1;             // 0..1 (16-pos group within 32)
    const int quad = (t >> 4) & 3, l15 = t & 15;

    const int g = t >> 7;              // GEN group 0..3 (wave-uniform)
    const int th = t & 127;
    const int gpos = th >> 2;          // 0..31
    const int gseg = th & 3;
    const int wo = (hh << 5) + gpos;
    const int spos = (ho << 6) + wo;
    const unsigned short* xh = xtfh + ((size_t)b << 20);

    // A fragment base: [step][chunk=quad][oc][8]; oc = ocg*64 + i*16 + l15
    const unsigned short* aBase = bw2 + quad * 2048 + (((ocg << 6) + l15) << 3);

    floatx4 acc[4];
#pragma unroll
    for (int i = 0; i < 4; i++) acc[i] = (floatx4){0.f, 0.f, 0.f, 0.f};

    // ---- prologue: this GEN group's taps {g, g+4, 8} offset/mask ----
    float om0s[3], om1s[3], omms[3];
#pragma unroll
    for (int s = 0; s < 3; ++s) {
        const int tap = (s == 2) ? 8 : (g + (s << 2));
        om0s[s] = offset[((size_t)(b * 18 + 2 * tap) << 12) + spos];
        om1s[s] = offset[((size_t)(b * 18 + 2 * tap + 1) << 12) + spos];
        omms[s] = mask[((size_t)(b * 9 + tap) << 12) + spos];
    }

    half8 aCur[4], aNxt[4];
    half8 crn[4];
    int yx[4];
    float ws[4];

#define MK(S) do { const int _tap = ((S) == 2) ? 8 : (g + ((S) << 2));      \
    mk_coords(_tap, ho, wo, om0s[S], om1s[S], omms[S],                      \
        yx[0], yx[1], yx[2], yx[3], ws[0], ws[1], ws[2], ws[3]); } while (0)

#define LOAD_CRN(C) do {                                                    \
    const int cb = ((C) << 5) + (gseg << 3);                                \
    crn[0] = *(const half8*)(xh + ((size_t)yx[0] << 8) + cb);               \
    crn[1] = *(const half8*)(xh + ((size_t)yx[1] << 8) + cb);               \
    crn[2] = *(const half8*)(xh + ((size_t)yx[2] << 8) + cb);               \
    crn[3] = *(const half8*)(xh + ((size_t)yx[3] << 8) + cb);               \
    } while (0)

#define GEN_WRITE(SLOT) do {                                                \
    float vals[8];                                                          \
    _Pragma("unroll")                                                       \
    for (int q = 0; q < 8; q++) {                                           \
        vals[q] = ws[0] * (float)crn[0][q] + ws[1] * (float)crn[1][q]       \
                + ws[2] * (float)crn[2][q] + ws[3] * (float)crn[3][q];      \
    }                                                                       \
    uintx4 pkH;                                                             \
    pack8(vals, pkH);                                                       \
    unsigned short* bp = Bs + (SLOT) * 1088 + gseg * 272 + (gpos << 3);     \
    *(uintx4*)bp = pkH;                                                     \
    } while (0)

#define LOAD_A(DST, STEP) do {                                              \
    const unsigned short* ap = aBase + (size_t)(STEP) * 8192;               \
    DST[0] = *(const half8*)ap;                                             \
    DST[1] = *(const half8*)(ap + 128);                                     \
    DST[2] = *(const half8*)(ap + 256);                                     \
    DST[3] = *(const half8*)(ap + 384);                                     \
    } while (0)

#define MFMA_STEP(SLOT, AREG) do {                                          \
    const unsigned short* Bp = Bs + (SLOT) * 1088 + quad * 272              \
                             + (pg << 7) + (l15 << 3);                      \
    const half8 bH = *(const half8*)Bp;                                     \
    acc[0] = MFMA16(AREG[0], bH, acc[0]);                                   \
    acc[1] = MFMA16(AREG[1], bH, acc[1]);                                   \
    acc[2] = MFMA16(AREG[2], bH, acc[2]);                                   \
    acc[3] = MFMA16(AREG[3], bH, acc[3]);                                   \
    } while (0)

    for (int c = 0; c < 8; ++c) {   // runtime loop (keeps code size in I$)
        // ---- GEN phase: group g does taps {g, g+4, 8(g0)} at chunk c ----
#pragma unroll
        for (int s = 0; s < 3; ++s) {
            if (s < 2 || g == 0) {             // wave-uniform guard
                MK(s);
                LOAD_CRN(c);
                GEN_WRITE((s == 2) ? 8 : (g + (s << 2)));
            }
        }
        __syncthreads();                       // all 9 Bs slots visible

        // ---- MFMA phase: 9 steps (step = tap*8 + c), 1-deep A-prefetch ----
        LOAD_A(aCur, c);
#pragma unroll
        for (int tp = 0; tp < 9; ++tp) {
            if (tp < 8) {
                if ((tp & 1) == 0) LOAD_A(aNxt, (tp + 1) * 8 + c);
                else               LOAD_A(aCur, (tp + 1) * 8 + c);
            }
            if ((tp & 1) == 0) MFMA_STEP(tp, aCur);
            else               MFMA_STEP(tp, aNxt);
        }
        __syncthreads();                       // all reads done before next GEN
    }

    // ---- epilogue: C/D col=l15 -> pos, row=quad*4+r -> oc; undo x64 ----
    float* outb = out + ((size_t)b << 20);
    const int posbase = (ho << 6) + (hh << 5) + (pg << 4);
#pragma unroll
    for (int i = 0; i < 4; i++) {
        const int ocb = (ocg << 6) + (i << 4) + (quad << 2);
#pragma unroll
        for (int r = 0; r < 4; r++) {
            const float bv = bias[ocb + r];
            const int pos = posbase + l15;
            outb[((size_t)(ocb + r) << 12) + pos] = acc[i][r] * 0.015625f + bv;
        }
    }
#undef MK
#undef LOAD_CRN
#undef GEN_WRITE
#undef LOAD_A
#undef MFMA_STEP
}

// ---- fallback (no workspace): R8-proven 3-product path, unchanged ----
__device__ __forceinline__ void split_f16_bits(float v, unsigned int& h, unsigned int& l) {
    _Float16 hf = (_Float16)v;
    float hff = (float)hf;
    _Float16 lf = (_Float16)(v - hff);
    union { _Float16 f; unsigned short s; } a2, b2;
    a2.f = hf; b2.f = lf;
    h = a2.s; l = b2.s;
}
__device__ __forceinline__ void split_pack8(const float* vals, uintx4& pkH, uintx4& pkL) {
#pragma unroll
    for (int p = 0; p < 4; p++) {
        float v0 = vals[2 * p], v1 = vals[2 * p + 1];
        fp16x2 h = __builtin_amdgcn_cvt_pkrtz(v0, v1);
        float h0 = (float)h[0], h1 = (float)h[1];
        fp16x2 l = __builtin_amdgcn_cvt_pkrtz(v0 - h0, v1 - h1);
        union { fp16x2 v; unsigned int u; } ch, cl;
        ch.v = h; cl.v = l;
        pkH[p] = ch.u;
        pkL[p] = cl.u;
    }
}

__global__ __launch_bounds__(256, 2) void k_dcn_fb(
    const float* __restrict__ x, const float* __restrict__ offset,
    const float* __restrict__ mask, const float* __restrict__ weight,
    const float* __restrict__ bias, float* __restrict__ out)
{
    __shared__ __align__(16) unsigned short AsH[256 * 40];
    __shared__ __align__(16) unsigned short AsL[256 * 40];
    __shared__ __align__(16) unsigned short BsH[64 * 40];
    __shared__ __align__(16) unsigned short BsL[64 * 40];
    __shared__ int cY[64][4];
    __shared__ float cW[64][4];

    const int t = threadIdx.x;
    const int tile = blockIdx.x;
    const int b = tile >> 6;
    const int ho = tile & 63;
    const int lane = t & 63, wid = t >> 6, quad = lane >> 4, l15 = lane & 15;
    const int gpos = t >> 2, gseg = t & 3;

    floatx4 acc[4][4];
#pragma unroll
    for (int i = 0; i < 4; i++)
#pragma unroll
        for (int j = 0; j < 4; j++) acc[i][j] = (floatx4){0.f, 0.f, 0.f, 0.f};

    for (int ktap = 0; ktap < 9; ++ktap) {
        __syncthreads();
        if (t < 64) {
            int wo = t;
            int spos = (ho << 6) + wo;
            float offy = offset[(((size_t)(b * 18 + 2 * ktap)) << 12) + spos];
            float offx = offset[(((size_t)(b * 18 + 2 * ktap + 1)) << 12) + spos];
            float m = mask[(((size_t)(b * 9 + ktap)) << 12) + spos];
            int c0, c1, c2, c3; float u0, u1, u2, u3;
            mk_coords(ktap, ho, wo, offy, offx, m, c0, c1, c2, c3, u0, u1, u2, u3);
            cY[t][0] = c0; cY[t][1] = c1; cY[t][2] = c2; cY[t][3] = c3;
            cW[t][0] = u0; cW[t][1] = u1; cW[t][2] = u2; cW[t][3] = u3;
        }
        __syncthreads();
        const int yx00 = cY[gpos][0], yx01 = cY[gpos][1];
        const int yx10 = cY[gpos][2], yx11 = cY[gpos][3];
        const float w00 = cW[gpos][0], w01 = cW[gpos][1];
        const float w10 = cW[gpos][2], w11 = cW[gpos][3];

        for (int cs = 0; cs < 8; ++cs) {
            const int c0 = cs << 5;
            {
                const float* wp = weight + (size_t)t * 2304 + (size_t)c0 * 9 + ktap;
#pragma unroll
                for (int kj = 0; kj < 32; kj += 2) {
                    unsigned int h0, l0u, h1, l1u;
                    split_f16_bits(wp[kj * 9] * 64.f, h0, l0u);
                    split_f16_bits(wp[kj * 9 + 9] * 64.f, h1, l1u);
                    *(unsigned int*)&AsH[t * 40 + kj] = h0 | (h1 << 16);
                    *(unsigned int*)&AsL[t * 40 + kj] = l0u | (l1u << 16);
                }
            }
            {
                const int cb = c0 + (gseg << 3);
                const float* xg = x + ((size_t)b << 20);
                float vals[8];
#pragma unroll
                for (int j = 0; j < 8; j++) {
                    const float* xc = xg + ((size_t)(cb + j) << 12);
                    vals[j] = w00 * xc[yx00] + w01 * xc[yx01] +
                              w10 * xc[yx10] + w11 * xc[yx11];
                }
                uintx4 pkH, pkL;
                split_pack8(vals, pkH, pkL);
                *(uintx4*)&BsH[gpos * 40 + (gseg << 3)] = pkH;
                *(uintx4*)&BsL[gpos * 40 + (gseg << 3)] = pkL;
            }
            __syncthreads();
            half8 aH[4], aL[4], bH[4], bL[4];
#pragma unroll
            for (int i = 0; i < 4; i++) {
                const int rowA = (wid << 6) + (i << 4) + l15;
                aH[i] = *(const half8*)&AsH[rowA * 40 + (quad << 3)];
                aL[i] = *(const half8*)&AsL[rowA * 40 + (quad << 3)];
            }
#pragma unroll
            for (int j = 0; j < 4; j++) {
                const int rowB = (j << 4) + l15;
                bH[j] = *(const half8*)&BsH[rowB * 40 + (quad << 3)];
                bL[j] = *(const half8*)&BsL[rowB * 40 + (quad << 3)];
            }
#pragma unroll
            for (int i = 0; i < 4; i++)
#pragma unroll
                for (int j = 0; j < 4; j++) {
                    acc[i][j] = MFMA16(aH[i], bH[j], acc[i][j]);
                    acc[i][j] = MFMA16(aL[i], bH[j], acc[i][j]);
                    acc[i][j] = MFMA16(aH[i], bL[j], acc[i][j]);
                }
            __syncthreads();
        }
    }
    float* outb = out + ((size_t)b << 20);
    const int posbase = ho << 6;
#pragma unroll
    for (int i = 0; i < 4; i++) {
        const int ocb = (wid << 6) + (i << 4) + (quad << 2);
#pragma unroll
        for (int r = 0; r < 4; r++) {
            const float bv = bias[ocb + r];
#pragma unroll
            for (int j = 0; j < 4; j++) {
                const int pos = posbase + (j << 4) + l15;
                outb[((size_t)(ocb + r) << 12) + pos] = acc[i][j][r] * 0.015625f + bv;
            }
        }
    }
}

extern "C" void kernel_launch(void* const* d_in, const int* in_sizes, int n_in,
                              void* d_out, int out_size, void* d_ws, size_t ws_size,
                              hipStream_t stream) {
    const float* x      = (const float*)d_in[0];
    const float* offset = (const float*)d_in[1];
    const float* mask   = (const float*)d_in[2];
    const float* weight = (const float*)d_in[3];
    const float* bias   = (const float*)d_in[4];
    float* out = (float*)d_out;

    const size_t xtf_bytes = (size_t)8 * 4096 * 256 * 2;       // 16 MB fp16
    const size_t bw2_elems = (size_t)72 * 8192;                // 589824 ush
    const size_t need = xtf_bytes + bw2_elems * 2;             // ~17.1 MB

    if (ws_size >= need) {
        unsigned short* xtfh = (unsigned short*)d_ws;
        unsigned short* bw2 = (unsigned short*)((char*)d_ws + xtf_bytes);
        k_prep<<<2048 + 2304, 256, 0, stream>>>(x, weight, xtfh, bw2);
        k_dcn_v19<<<1024, 512, 0, stream>>>(offset, mask, bias, xtfh, bw2, out);
    } else {
        k_dcn_fb<<<512, 256, 0, stream>>>(x, offset, mask, weight, bias, out);
    }
}

// Round 18
// 149.154 us; speedup vs baseline: 1.6629x; 1.2260x over previous
//
#include <hip/hip_runtime.h>
#include <stdint.h>

// DCNv2 fused forward (B=8, C=256, H=W=64, OC=256, 3x3, pad=1, stride=1, DG=1)
// R23 = FINAL: exact revert to R17 (Round 12, measured 148.0 us total,
// main 65.7 us, PASS at absmax 2^-7 vs 2.86e-2 gate).
// Why this config won (evidence across R8-R22):
//  - Tiling 256oc x 64pos per block, grid 512: L2-traffic-minimal partition.
//    A (bw2) read once per block = 590 MB; corners = 604 MB (bilinear 4x,
//    irreducible); ~1.2 GB L2 ~= 35 us floor. The pos-split geometry
//    (R19-R22) quadrupled A-traffic to 2.4 GB -> 108 us even spill-free.
//  - Chunk-major phases (c=0..7): preserves 32B column streaming of xtf
//    (tap-major blew L2: R12), 9 barrier pairs.
//  - 512 threads, 8 waves x 32oc: occupancy 36% (2 blocks/CU), VGPR 64.
//  - In-phase 1-deep prefetch only. Cross-barrier/backedge VMEM prefetch is
//    empirically cursed on this toolchain (R5/R10/R11 all failed sparse).
//  - Single-product fp16 GEMM (weights x64, /64 epilogue): error ~2^-7,
//    3.7x under gate; halves data plane vs hi/lo (R14->R16 = 2x speedup).
// Fallbacks: no-workspace -> R8-proven direct kernel.

typedef __attribute__((ext_vector_type(8))) _Float16 half8;
typedef __attribute__((ext_vector_type(2))) __fp16 fp16x2;
typedef __attribute__((ext_vector_type(4))) float floatx4;
typedef __attribute__((ext_vector_type(4))) unsigned int uintx4;

#define MFMA16(A, B, C) __builtin_amdgcn_mfma_f32_16x16x32_f16(A, B, C, 0, 0, 0)

__device__ __forceinline__ unsigned short f16_bits_rne(float v) {
    _Float16 hf = (_Float16)v;               // v_cvt_f16_f32 (RNE)
    union { _Float16 f; unsigned short s; } a; a.f = hf;
    return a.s;
}

// pack 8 f32 -> 8 fp16 (4x cvt_pkrtz)
__device__ __forceinline__ void pack8(const float* vals, uintx4& pkH) {
#pragma unroll
    for (int p = 0; p < 4; p++) {
        fp16x2 h = __builtin_amdgcn_cvt_pkrtz(vals[2 * p], vals[2 * p + 1]);
        union { fp16x2 v; unsigned int u; } ch; ch.v = h;
        pkH[p] = ch.u;
    }
}

__device__ __forceinline__ void mk_coords(int tap, int ho, int wo,
    float offy, float offx, float m,
    int& yx00, int& yx01, int& yx10, int& yx11,
    float& w00, float& w01, float& w10, float& w11) {
    float py = (float)(tap / 3) + (float)(ho - 1) + offy;
    float px = (float)(tap % 3) + (float)(wo - 1) + offx;
    float y0f = floorf(py), x0f = floorf(px);
    float wy1 = py - y0f, wx1 = px - x0f;
    float wy0 = 1.f - wy1, wx0 = 1.f - wx1;
    int y0 = (int)y0f, x0 = (int)x0f, y1 = y0 + 1, x1 = x0 + 1;
    bool vy0 = (y0 >= 0) && (y0 < 64), vy1 = (y1 >= 0) && (y1 < 64);
    bool vx0 = (x0 >= 0) && (x0 < 64), vx1 = (x1 >= 0) && (x1 < 64);
    int cy0 = min(max(y0, 0), 63), cy1 = min(max(y1, 0), 63);
    int cx0 = min(max(x0, 0), 63), cx1 = min(max(x1, 0), 63);
    yx00 = cy0 * 64 + cx0; yx01 = cy0 * 64 + cx1;
    yx10 = cy1 * 64 + cx0; yx11 = cy1 * 64 + cx1;
    w00 = wy0 * wx0 * m * ((vy0 && vx0) ? 1.f : 0.f);
    w01 = wy0 * wx1 * m * ((vy0 && vx1) ? 1.f : 0.f);
    w10 = wy1 * wx0 * m * ((vy1 && vx0) ? 1.f : 0.f);
    w11 = wy1 * wx1 * m * ((vy1 && vx1) ? 1.f : 0.f);
}

// ---- fused prep: blocks 0..2047 transpose x -> xtfh fp16;
//      blocks 2048..4351 weight*64 -> bw2 hi-only fp16 ----
__global__ __launch_bounds__(256) void k_prep(const float* __restrict__ x,
                                              const float* __restrict__ w,
                                              unsigned short* __restrict__ xtfh,
                                              unsigned short* __restrict__ bw2) {
    __shared__ float T[64][65];
    const int blk = blockIdx.x;
    const int t = threadIdx.x;
    if (blk < 2048) {
        const int b = blk >> 8;
        const int ct = (blk >> 6) & 3;
        const int tt = blk & 63;
        const int jj = t & 63, i4 = t >> 6;
        const float* xb = x + ((size_t)b << 20);
#pragma unroll 4
        for (int ii = 0; ii < 16; ii++) {
            int i = ii * 4 + i4;
            T[i][jj] = xb[((size_t)(ct * 64 + i) << 12) + tt * 64 + jj];
        }
        __syncthreads();
        unsigned short* ob = xtfh + ((size_t)b << 20);
#pragma unroll 4
        for (int ii = 0; ii < 16; ii++) {
            int jo = ii * 4 + i4;
            ob[((size_t)(tt * 64 + jo) << 8) + ct * 64 + jj] = f16_bits_rne(T[jj][jo]);
        }
    } else {
        int tid = (blk - 2048) * 256 + t;   // 72*8192 = 589824
        int j = tid & 7;
        int oc = (tid >> 3) & 255;
        int c = (tid >> 11) & 3;
        int step = tid >> 13;
        int ktap = step >> 3;
        int ch = ((step & 7) << 5) + (c << 3) + j;
        float v = w[oc * 2304 + ch * 9 + ktap] * 64.f;
        bw2[tid] = f16_bits_rne(v);
    }
}

// ---- main (512 threads, chunk-major phases, single-product fp16) ----
__global__ __launch_bounds__(512, 4) void k_dcn_v14(
    const float* __restrict__ offset,  // (8,18,64,64)
    const float* __restrict__ mask,    // (8,9,64,64)
    const float* __restrict__ bias,    // (256,)
    const unsigned short* __restrict__ xtfh, // (8,4096,256) fp16
    const unsigned short* __restrict__ bw2,  // (72,4,256,8) fp16
    float* __restrict__ out)           // (8,256,64,64)
{
    // B region: [slot9(tap)][chunk4(stride 528)][pos64][8]; slot = 2112 ush
    __shared__ __align__(16) unsigned short Bs[9 * 2112];

    const int t = threadIdx.x;         // 0..511
    const int tile = blockIdx.x;       // 512
    const int b = tile & 7;            // XCD/L2 locality
    const int ho = tile >> 3;          // 0..63

    const int w8 = t >> 6, quad = (t >> 4) & 3, l15 = t & 15;
    const int grp = t >> 8;            // GEN tap-group (wave-uniform)
    const int th = t & 255;
    const int gpos = th >> 2, gseg = th & 3;
    const int wo = gpos;
    const int spos = (ho << 6) + wo;
    const unsigned short* xh = xtfh + ((size_t)b << 20);

    // A fragment base: [step][chunk=quad][oc][8]; oc = w8*32 + i*16 + l15
    const unsigned short* aBase = bw2 + quad * 2048 + (((w8 << 5) + l15) << 3);

    floatx4 acc[2][4];
#pragma unroll
    for (int i = 0; i < 2; i++)
#pragma unroll
        for (int j = 0; j < 4; j++) acc[i][j] = (floatx4){0.f, 0.f, 0.f, 0.f};

    // ---- prologue: this group's 5 tap-slots of offset/mask (tap = 2s+grp,
    //      clamped; grp1 slot4 is a harmless dup of tap 8, write-guarded) ----
    float om0s[5], om1s[5], omms[5];
#pragma unroll
    for (int s = 0; s < 5; ++s) {
        int tap = 2 * s + grp; if (tap > 8) tap = 8;
        om0s[s] = offset[((size_t)(b * 18 + 2 * tap) << 12) + spos];
        om1s[s] = offset[((size_t)(b * 18 + 2 * tap + 1) << 12) + spos];
        omms[s] = mask[((size_t)(b * 9 + tap) << 12) + spos];
    }

    half8 aCur[2], aNxt[2];
    half8 crnA[4], crnB[4];        // 4 corners x 8 fp16 channels
    int yxs[2][4];                 // ping-pong coord sets (static-indexed)
    float wss[2][4];

#define MK(S, SET) do { int _tap = 2 * (S) + grp; if (_tap > 8) _tap = 8;   \
    mk_coords(_tap, ho, wo, om0s[S], om1s[S], omms[S],                      \
        yxs[SET][0], yxs[SET][1], yxs[SET][2], yxs[SET][3],                 \
        wss[SET][0], wss[SET][1], wss[SET][2], wss[SET][3]); } while (0)

#define LOAD_CRN(DST, SET, C) do {                                          \
    const int cb = ((C) << 5) + (gseg << 3);                                \
    DST[0] = *(const half8*)(xh + ((size_t)yxs[SET][0] << 8) + cb);         \
    DST[1] = *(const half8*)(xh + ((size_t)yxs[SET][1] << 8) + cb);         \
    DST[2] = *(const half8*)(xh + ((size_t)yxs[SET][2] << 8) + cb);         \
    DST[3] = *(const half8*)(xh + ((size_t)yxs[SET][3] << 8) + cb);         \
    } while (0)

#define GEN_WRITE(CRN, SET, SLOT) do {                                      \
    float vals[8];                                                          \
    _Pragma("unroll")                                                       \
    for (int q = 0; q < 8; q++) {                                           \
        vals[q] = wss[SET][0] * (float)CRN[0][q]                            \
                + wss[SET][1] * (float)CRN[1][q]                            \
                + wss[SET][2] * (float)CRN[2][q]                            \
                + wss[SET][3] * (float)CRN[3][q];                           \
    }                                                                       \
    uintx4 pkH;                                                             \
    pack8(vals, pkH);                                                       \
    unsigned short* bp = Bs + (SLOT) * 2112 + gseg * 528 + (gpos << 3);     \
    *(uintx4*)bp = pkH;                                                     \
    } while (0)

#define LOAD_A(DST, STEP) do {                                              \
    const unsigned short* ap = aBase + (size_t)(STEP) * 8192;               \
    DST[0] = *(const half8*)ap;                                             \
    DST[1] = *(const half8*)(ap + 128);                                     \
    } while (0)

#define MFMA_STEP(SLOT, AREG) do {                                          \
    const unsigned short* Bp = Bs + (SLOT) * 2112 + quad * 528;             \
    half8 bH[4];                                                            \
    _Pragma("unroll")                                                       \
    for (int j = 0; j < 4; j++)                                             \
        bH[j] = *(const half8*)(Bp + (((j << 4) + l15) << 3));              \
    _Pragma("unroll")                                                       \
    for (int i = 0; i < 2; i++)                                             \
    _Pragma("unroll")                                                       \
        for (int j = 0; j < 4; j++)                                         \
            acc[i][j] = MFMA16(AREG[i], bH[j], acc[i][j]);                  \
    } while (0)

    for (int c = 0; c < 8; ++c) {   // runtime loop (keeps code size in I$)
        // ---- GEN phase: group grp does taps {2s+grp} -> Bs slots ----
        MK(0, 0);
        LOAD_CRN(crnA, 0, c);
#pragma unroll
        for (int s = 0; s < 5; ++s) {
            if (s < 4) {
                if ((s & 1) == 0) { MK(s + 1, 1); LOAD_CRN(crnB, 1, c); }
                else              { MK(s + 1, 0); LOAD_CRN(crnA, 0, c); }
            }
            const int slot = 2 * s + grp;
            if (s < 4 || grp == 0) {           // tap 9 (grp1,s4) skipped
                if ((s & 1) == 0) GEN_WRITE(crnA, 0, slot);
                else              GEN_WRITE(crnB, 1, slot);
            }
        }
        __syncthreads();                       // all 9 Bs slots visible

        // ---- MFMA phase: 9 steps (step = tap*8 + c), A 1-deep in-phase ----
        LOAD_A(aCur, c);
#pragma unroll
        for (int tp = 0; tp < 9; ++tp) {
            if (tp < 8) {
                if ((tp & 1) == 0) LOAD_A(aNxt, (tp + 1) * 8 + c);
                else               LOAD_A(aCur, (tp + 1) * 8 + c);
            }
            if ((tp & 1) == 0) MFMA_STEP(tp, aCur);
            else               MFMA_STEP(tp, aNxt);
        }
        __syncthreads();                       // all reads done before next GEN
    }

    // ---- epilogue: C/D col=l15 -> pos, row=quad*4+r -> oc; undo x64 ----
    float* outb = out + ((size_t)b << 20);
    const int posbase = ho << 6;
#pragma unroll
    for (int i = 0; i < 2; i++) {
        const int ocb = (w8 << 5) + (i << 4) + (quad << 2);
#pragma unroll
        for (int r = 0; r < 4; r++) {
            const float bv = bias[ocb + r];
#pragma unroll
            for (int j = 0; j < 4; j++) {
                const int pos = posbase + (j << 4) + l15;
                outb[((size_t)(ocb + r) << 12) + pos] = acc[i][j][r] * 0.015625f + bv;
            }
        }
    }
#undef MK
#undef LOAD_CRN
#undef GEN_WRITE
#undef LOAD_A
#undef MFMA_STEP
}

// ---- fallback (no workspace): R8-proven 3-product path, unchanged ----
__device__ __forceinline__ void split_f16_bits(float v, unsigned int& h, unsigned int& l) {
    _Float16 hf = (_Float16)v;
    float hff = (float)hf;
    _Float16 lf = (_Float16)(v - hff);
    union { _Float16 f; unsigned short s; } a2, b2;
    a2.f = hf; b2.f = lf;
    h = a2.s; l = b2.s;
}
__device__ __forceinline__ void split_pack8(const float* vals, uintx4& pkH, uintx4& pkL) {
#pragma unroll
    for (int p = 0; p < 4; p++) {
        float v0 = vals[2 * p], v1 = vals[2 * p + 1];
        fp16x2 h = __builtin_amdgcn_cvt_pkrtz(v0, v1);
        float h0 = (float)h[0], h1 = (float)h[1];
        fp16x2 l = __builtin_amdgcn_cvt_pkrtz(v0 - h0, v1 - h1);
        union { fp16x2 v; unsigned int u; } ch, cl;
        ch.v = h; cl.v = l;
        pkH[p] = ch.u;
        pkL[p] = cl.u;
    }
}

__global__ __launch_bounds__(256, 2) void k_dcn_fb(
    const float* __restrict__ x, const float* __restrict__ offset,
    const float* __restrict__ mask, const float* __restrict__ weight,
    const float* __restrict__ bias, float* __restrict__ out)
{
    __shared__ __align__(16) unsigned short AsH[256 * 40];
    __shared__ __align__(16) unsigned short AsL[256 * 40];
    __shared__ __align__(16) unsigned short BsH[64 * 40];
    __shared__ __align__(16) unsigned short BsL[64 * 40];
    __shared__ int cY[64][4];
    __shared__ float cW[64][4];

    const int t = threadIdx.x;
    const int tile = blockIdx.x;   // 512
    const int b = tile >> 6;
    const int ho = tile & 63;
    const int lane = t & 63, wid = t >> 6, quad = lane >> 4, l15 = lane & 15;
    const int gpos = t >> 2, gseg = t & 3;

    floatx4 acc[4][4];
#pragma unroll
    for (int i = 0; i < 4; i++)
#pragma unroll
        for (int j = 0; j < 4; j++) acc[i][j] = (floatx4){0.f, 0.f, 0.f, 0.f};

    for (int ktap = 0; ktap < 9; ++ktap) {
        __syncthreads();
        if (t < 64) {
            int wo = t;
            int spos = (ho << 6) + wo;
            float offy = offset[(((size_t)(b * 18 + 2 * ktap)) << 12) + spos];
            float offx = offset[(((size_t)(b * 18 + 2 * ktap + 1)) << 12) + spos];
            float m = mask[(((size_t)(b * 9 + ktap)) << 12) + spos];
            int c0, c1, c2, c3; float u0, u1, u2, u3;
            mk_coords(ktap, ho, wo, offy, offx, m, c0, c1, c2, c3, u0, u1, u2, u3);
            cY[t][0] = c0; cY[t][1] = c1; cY[t][2] = c2; cY[t][3] = c3;
            cW[t][0] = u0; cW[t][1] = u1; cW[t][2] = u2; cW[t][3] = u3;
        }
        __syncthreads();
        const int yx00 = cY[gpos][0], yx01 = cY[gpos][1];
        const int yx10 = cY[gpos][2], yx11 = cY[gpos][3];
        const float w00 = cW[gpos][0], w01 = cW[gpos][1];
        const float w10 = cW[gpos][2], w11 = cW[gpos][3];

        for (int cs = 0; cs < 8; ++cs) {
            const int c0 = cs << 5;
            {
                const float* wp = weight + (size_t)t * 2304 + (size_t)c0 * 9 + ktap;
#pragma unroll
                for (int kj = 0; kj < 32; kj += 2) {
                    unsigned int h0, l0u, h1, l1u;
                    split_f16_bits(wp[kj * 9] * 64.f, h0, l0u);
                    split_f16_bits(wp[kj * 9 + 9] * 64.f, h1, l1u);
                    *(unsigned int*)&AsH[t * 40 + kj] = h0 | (h1 << 16);
                    *(unsigned int*)&AsL[t * 40 + kj] = l0u | (l1u << 16);
                }
            }
            {
                const int cb = c0 + (gseg << 3);
                const float* xg = x + ((size_t)b << 20);
                float vals[8];
#pragma unroll
                for (int j = 0; j < 8; j++) {
                    const float* xc = xg + ((size_t)(cb + j) << 12);
                    vals[j] = w00 * xc[yx00] + w01 * xc[yx01] +
                              w10 * xc[yx10] + w11 * xc[yx11];
                }
                uintx4 pkH, pkL;
                split_pack8(vals, pkH, pkL);
                *(uintx4*)&BsH[gpos * 40 + (gseg << 3)] = pkH;
                *(uintx4*)&BsL[gpos * 40 + (gseg << 3)] = pkL;
            }
            __syncthreads();
            half8 aH[4], aL[4], bH[4], bL[4];
#pragma unroll
            for (int i = 0; i < 4; i++) {
                const int rowA = (wid << 6) + (i << 4) + l15;
                aH[i] = *(const half8*)&AsH[rowA * 40 + (quad << 3)];
                aL[i] = *(const half8*)&AsL[rowA * 40 + (quad << 3)];
            }
#pragma unroll
            for (int j = 0; j < 4; j++) {
                const int rowB = (j << 4) + l15;
                bH[j] = *(const half8*)&BsH[rowB * 40 + (quad << 3)];
                bL[j] = *(const half8*)&BsL[rowB * 40 + (quad << 3)];
            }
#pragma unroll
            for (int i = 0; i < 4; i++)
#pragma unroll
                for (int j = 0; j < 4; j++) {
                    acc[i][j] = MFMA16(aH[i], bH[j], acc[i][j]);
                    acc[i][j] = MFMA16(aL[i], bH[j], acc[i][j]);
                    acc[i][j] = MFMA16(aH[i], bL[j], acc[i][j]);
                }
            __syncthreads();
        }
    }
    float* outb = out + ((size_t)b << 20);
    const int posbase = ho << 6;
#pragma unroll
    for (int i = 0; i < 4; i++) {
        const int ocb = (wid << 6) + (i << 4) + (quad << 2);
#pragma unroll
        for (int r = 0; r < 4; r++) {
            const float bv = bias[ocb + r];
#pragma unroll
            for (int j = 0; j < 4; j++) {
                const int pos = posbase + (j << 4) + l15;
                outb[((size_t)(ocb + r) << 12) + pos] = acc[i][j][r] * 0.015625f + bv;
            }
        }
    }
}

extern "C" void kernel_launch(void* const* d_in, const int* in_sizes, int n_in,
                              void* d_out, int out_size, void* d_ws, size_t ws_size,
                              hipStream_t stream) {
    const float* x      = (const float*)d_in[0];
    const float* offset = (const float*)d_in[1];
    const float* mask   = (const float*)d_in[2];
    const float* weight = (const float*)d_in[3];
    const float* bias   = (const float*)d_in[4];
    float* out = (float*)d_out;

    const size_t xtf_bytes = (size_t)8 * 4096 * 256 * 2;       // 16 MB fp16
    const size_t bw2_elems = (size_t)72 * 8192;                // 589824 ush
    const size_t need = xtf_bytes + bw2_elems * 2;             // ~17.1 MB

    if (ws_size >= need) {
        unsigned short* xtfh = (unsigned short*)d_ws;
        unsigned short* bw2 = (unsigned short*)((char*)d_ws + xtf_bytes);
        k_prep<<<2048 + 2304, 256, 0, stream>>>(x, weight, xtfh, bw2);
        k_dcn_v14<<<512, 512, 0, stream>>>(offset, mask, bias, xtfh, bw2, out);
    } else {
        k_dcn_fb<<<512, 256, 0, stream>>>(x, offset, mask, weight, bias, out);
    }
}